// Round 1
// baseline (409.027 us; speedup 1.0000x reference)
//
#include <hip/hip_runtime.h>

// ExpandHarmonics: N rows, each expands into MAX_MULT=5 harmonic candidates.
// Outputs concatenated flat in d_out (all written as float32 values):
//   [0,15N)   hkl_all   (N,5,3)  ints as floats
//   [15N,20N) wavelength_all (N,5,1)
//   [20N,25N) d_all     (N,5,1)
//   [25N,30N) refl_id   (N,5,1)  ints as floats (max ~7.09e6 < 2^24, exact)

constexpr int kHmax = 60;
constexpr int kG    = 2 * kHmax + 1;     // 121
constexpr int kG3   = kG * kG * kG;      // 1,771,561
constexpr int kMult = 5;

__global__ __launch_bounds__(256) void expand_harmonics(
    const int*   __restrict__ asu_id,
    const int*   __restrict__ hkl,
    const float* __restrict__ wavelength,
    const float* __restrict__ dmin,
    const float* __restrict__ Bmat,
    const int*   __restrict__ refl_table,
    float*       __restrict__ out,
    int N)
{
#pragma clang fp contract(off)
    int i = blockIdx.x * blockDim.x + threadIdx.x;
    if (i >= N) return;

    float* out_hkl = out;
    float* out_wl  = out + (long long)15 * N;
    float* out_d   = out + (long long)20 * N;
    float* out_id  = out + (long long)25 * N;

    int asu = asu_id[i];
    int h = hkl[3 * i + 0];
    int k = hkl[3 * i + 1];
    int l = hkl[3 * i + 2];
    float wl = wavelength[i];
    bool mask = (h | k | l) != 0;

    // gcd(|h|,|k|,|l|)
    int a = h < 0 ? -h : h;
    int b = k < 0 ? -k : k;
    int c = l < 0 ? -l : l;
    while (b) { int t = a % b; a = b; b = t; }
    while (c) { int t = a % c; a = c; c = t; }
    int n_safe = a > 1 ? a : 1;

    int h0 = h / n_safe, k0 = k / n_safe, l0 = l / n_safe;  // exact division
    float wl0 = wl * (float)n_safe;
    float dmin_g = dmin[asu];

    const float* Ba = Bmat + asu * 9;
    float fh = (float)h0, fk = (float)k0, fl = (float)l0;
    // match numpy einsum order: ((B0*h + B1*k) + B2*l), no FMA contraction
    float s0 = Ba[0] * fh + Ba[1] * fk + Ba[2] * fl;
    float s1 = Ba[3] * fh + Ba[4] * fk + Ba[5] * fl;
    float s2 = Ba[6] * fh + Ba[7] * fk + Ba[8] * fl;
    float nrm = sqrtf(s0 * s0 + s1 * s1 + s2 * s2);
    float d0 = 1.0f / fmaxf(nrm, 1e-6f);

    float n_max = fminf(floorf(d0 / dmin_g), floorf(wl0 / 0.95f));
    float n_min = floorf(wl0 / 1.25f) + 1.0f;

    const int tb = asu * kG3;
    #pragma unroll
    for (int j = 0; j < kMult; ++j) {
        float njf = n_min + (float)j;
        if (njf > n_max) njf = 0.0f;
        int nj = (int)njf;
        int ha = h0 * nj, ka = k0 * nj, la = l0 * nj;
        int i0 = ha + kHmax, i1 = ka + kHmax, i2 = la + kHmax;
        int rid = -1;
        if ((unsigned)i0 < (unsigned)kG &&
            (unsigned)i1 < (unsigned)kG &&
            (unsigned)i2 < (unsigned)kG) {
            rid = refl_table[tb + i0 * (kG * kG) + i1 * kG + i2];
        }
        bool absent = rid < 0;
        if (absent) { ha = 0; ka = 0; la = 0; }
        float n_inv  = absent ? 0.0f : (1.0f / fmaxf((float)nj, 1e-6f));
        float d_all  = d0 * n_inv;
        float wl_all = wl0 * n_inv;
        float ridf   = (float)rid;
        if (!mask) { ha = 0; ka = 0; la = 0; d_all = 0.0f; wl_all = 0.0f; ridf = 0.0f; }

        long long rb = (long long)i * 15 + j * 3;
        out_hkl[rb + 0] = (float)ha;
        out_hkl[rb + 1] = (float)ka;
        out_hkl[rb + 2] = (float)la;
        long long r5 = (long long)i * 5 + j;
        out_wl[r5] = wl_all;
        out_d[r5]  = d_all;
        out_id[r5] = ridf;
    }
}

extern "C" void kernel_launch(void* const* d_in, const int* in_sizes, int n_in,
                              void* d_out, int out_size, void* d_ws, size_t ws_size,
                              hipStream_t stream) {
    const int*   asu_id = (const int*)d_in[0];
    const int*   hkl    = (const int*)d_in[1];
    const float* wl     = (const float*)d_in[2];
    const float* dmin   = (const float*)d_in[3];
    const float* B      = (const float*)d_in[4];
    const int*   refl   = (const int*)d_in[5];
    float* out = (float*)d_out;
    int N = in_sizes[0];  // asu_id is (N,1)

    int threads = 256;
    int blocks = (N + threads - 1) / threads;
    hipLaunchKernelGGL(expand_harmonics, dim3(blocks), dim3(threads), 0, stream,
                       asu_id, hkl, wl, dmin, B, refl, out, N);
}

// Round 2
// 299.585 us; speedup vs baseline: 1.3653x; 1.3653x over previous
//
#include <hip/hip_runtime.h>

// ExpandHarmonics: N rows -> 5 harmonic candidates each.
// Outputs concatenated flat in d_out (all float32 values):
//   [0,15N)   hkl_all   (N,5,3)  ints as floats
//   [15N,20N) wavelength_all (N,5,1)
//   [20N,25N) d_all     (N,5,1)
//   [25N,30N) refl_id   (N,5,1)  ints as floats (max ~7.09e6 < 2^24, exact)
//
// R2: stage per-block outputs in LDS, write out with coalesced float4 stores.
// R1 had WRITE_SIZE = 3x output size (partial-line write amplification from
// lane-stride-15/5 scalar stores).

constexpr int kHmax = 60;
constexpr int kG    = 2 * kHmax + 1;     // 121
constexpr int kG3   = kG * kG * kG;      // 1,771,561
constexpr int kT    = 256;               // block size

__global__ __launch_bounds__(kT) void expand_harmonics(
    const int*   __restrict__ asu_id,
    const int*   __restrict__ hkl,
    const float* __restrict__ wavelength,
    const float* __restrict__ dmin,
    const float* __restrict__ Bmat,
    const int*   __restrict__ refl_table,
    float*       __restrict__ out,
    int N)
{
#pragma clang fp contract(off)
    __shared__ float s_hkl[kT * 15];   // 15 KB
    __shared__ float s_wl [kT * 5];    // 5 KB
    __shared__ float s_d  [kT * 5];    // 5 KB
    __shared__ float s_id [kT * 5];    // 5 KB

    const int tid  = threadIdx.x;
    const int base = blockIdx.x * kT;
    const int i    = base + tid;

    if (i < N) {
        int asu = asu_id[i];
        int h = hkl[3 * i + 0];
        int k = hkl[3 * i + 1];
        int l = hkl[3 * i + 2];
        float wl = wavelength[i];
        bool mask = (h | k | l) != 0;

        // gcd(|h|,|k|,|l|)
        int a = h < 0 ? -h : h;
        int b = k < 0 ? -k : k;
        int c = l < 0 ? -l : l;
        while (b) { int t = a % b; a = b; b = t; }
        while (c) { int t = a % c; a = c; c = t; }
        int n_safe = a > 1 ? a : 1;

        int h0 = h / n_safe, k0 = k / n_safe, l0 = l / n_safe;  // exact
        float wl0 = wl * (float)n_safe;
        float dmin_g = dmin[asu];

        const float* Ba = Bmat + asu * 9;
        float fh = (float)h0, fk = (float)k0, fl = (float)l0;
        // match numpy order, no FMA contraction
        float s0 = Ba[0] * fh + Ba[1] * fk + Ba[2] * fl;
        float s1 = Ba[3] * fh + Ba[4] * fk + Ba[5] * fl;
        float s2 = Ba[6] * fh + Ba[7] * fk + Ba[8] * fl;
        float nrm = sqrtf(s0 * s0 + s1 * s1 + s2 * s2);
        float d0 = 1.0f / fmaxf(nrm, 1e-6f);

        float n_max = fminf(floorf(d0 / dmin_g), floorf(wl0 / 0.95f));
        float n_min = floorf(wl0 / 1.25f) + 1.0f;

        const int tb = asu * kG3;
        #pragma unroll
        for (int j = 0; j < 5; ++j) {
            float njf = n_min + (float)j;
            if (njf > n_max) njf = 0.0f;
            int nj = (int)njf;
            int ha = h0 * nj, ka = k0 * nj, la = l0 * nj;
            int i0 = ha + kHmax, i1 = ka + kHmax, i2 = la + kHmax;
            int rid = -1;
            if ((unsigned)i0 < (unsigned)kG &&
                (unsigned)i1 < (unsigned)kG &&
                (unsigned)i2 < (unsigned)kG) {
                rid = refl_table[tb + i0 * (kG * kG) + i1 * kG + i2];
            }
            bool absent = rid < 0;
            if (absent) { ha = 0; ka = 0; la = 0; }
            float n_inv  = absent ? 0.0f : (1.0f / fmaxf((float)nj, 1e-6f));
            float d_all  = d0 * n_inv;
            float wl_all = wl0 * n_inv;
            float ridf   = (float)rid;
            if (!mask) { ha = 0; ka = 0; la = 0; d_all = 0.0f; wl_all = 0.0f; ridf = 0.0f; }

            int rb = tid * 15 + j * 3;        // stride 15: 2-way bank alias, free
            s_hkl[rb + 0] = (float)ha;
            s_hkl[rb + 1] = (float)ka;
            s_hkl[rb + 2] = (float)la;
            int r5 = tid * 5 + j;             // stride 5: 2-way alias, free
            s_wl[r5] = wl_all;
            s_d [r5] = d_all;
            s_id[r5] = ridf;
        }
    }

    __syncthreads();

    float* out_hkl = out + (long long)base * 15;
    float* out_wl  = out + (long long)15 * N + (long long)base * 5;
    float* out_d   = out + (long long)20 * N + (long long)base * 5;
    float* out_id  = out + (long long)25 * N + (long long)base * 5;

    const int valid = min(kT, N - base);
    if (valid == kT) {
        // full block: coalesced float4 stores (all bases 16B-aligned:
        // base*15*4 = blk*15360, 15N*4/20N*4/25N*4 all %16==0, base*5*4=blk*5120)
        const float4* v_hkl = (const float4*)s_hkl;   // 960 float4
        const float4* v_wl  = (const float4*)s_wl;    // 320 float4
        const float4* v_d   = (const float4*)s_d;
        const float4* v_id  = (const float4*)s_id;
        float4* g_hkl = (float4*)out_hkl;
        float4* g_wl  = (float4*)out_wl;
        float4* g_d   = (float4*)out_d;
        float4* g_id  = (float4*)out_id;
        #pragma unroll
        for (int r = 0; r < 4; ++r) {
            int idx = r * kT + tid;
            if (idx < 960) g_hkl[idx] = v_hkl[idx];
        }
        #pragma unroll
        for (int r = 0; r < 2; ++r) {
            int idx = r * kT + tid;
            if (idx < 320) {
                g_wl[idx] = v_wl[idx];
                g_d [idx] = v_d [idx];
                g_id[idx] = v_id[idx];
            }
        }
    } else {
        // tail block: scalar coalesced stores
        for (int idx = tid; idx < valid * 15; idx += kT) out_hkl[idx] = s_hkl[idx];
        for (int idx = tid; idx < valid * 5;  idx += kT) {
            out_wl[idx] = s_wl[idx];
            out_d [idx] = s_d [idx];
            out_id[idx] = s_id[idx];
        }
    }
}

extern "C" void kernel_launch(void* const* d_in, const int* in_sizes, int n_in,
                              void* d_out, int out_size, void* d_ws, size_t ws_size,
                              hipStream_t stream) {
    const int*   asu_id = (const int*)d_in[0];
    const int*   hkl    = (const int*)d_in[1];
    const float* wl     = (const float*)d_in[2];
    const float* dmin   = (const float*)d_in[3];
    const float* B      = (const float*)d_in[4];
    const int*   refl   = (const int*)d_in[5];
    float* out = (float*)d_out;
    int N = in_sizes[0];  // asu_id is (N,1)

    int blocks = (N + kT - 1) / kT;
    hipLaunchKernelGGL(expand_harmonics, dim3(blocks), dim3(kT), 0, stream,
                       asu_id, hkl, wl, dmin, B, refl, out, N);
}